// Round 1
// baseline (227.092 us; speedup 1.0000x reference)
//
#include <hip/hip_runtime.h>

#define BATCH 4
#define SEQ   4096
#define DIM   1024
#define EPS_F 1e-6f

typedef __bf16 bf16_t;
typedef bf16_t bf16x8 __attribute__((ext_vector_type(8)));
typedef float  f32x4  __attribute__((ext_vector_type(4)));
typedef unsigned short u16x8 __attribute__((ext_vector_type(8)));

__device__ __forceinline__ unsigned short f2bf(float f) {
  unsigned u = __float_as_uint(f);
  u += 0x7FFFu + ((u >> 16) & 1u);          // round-to-nearest-even
  return (unsigned short)(u >> 16);
}
__device__ __forceinline__ float bf2f(unsigned short h) {
  return __uint_as_float(((unsigned)h) << 16);
}
__device__ __forceinline__ float phi_f(float x) {
  return x > 0.f ? x + 1.f : __expf(x);     // elu(x)+1
}

// ---- transpose (+ optional phi) fp32 [rows][cols] -> bf16 [cols][rows] ----
template<bool PHI>
__global__ __launch_bounds__(256) void phi_transpose(const float* __restrict__ in,
    unsigned short* __restrict__ out, int rows, int cols) {
  __shared__ float t[32][33];
  const int bx = blockIdx.x * 32;          // col base
  const int by = blockIdx.y * 32;          // row base
  const size_t bo = (size_t)blockIdx.z * rows * cols;
  const int x = threadIdx.x, y = threadIdx.y;
  #pragma unroll
  for (int j = 0; j < 32; j += 8) {
    float v = in[bo + (size_t)(by + y + j) * cols + bx + x];
    if (PHI) v = phi_f(v);
    t[y + j][x] = v;
  }
  __syncthreads();
  #pragma unroll
  for (int j = 0; j < 32; j += 8)
    out[bo + (size_t)(bx + y + j) * rows + by + x] = f2bf(t[x][y + j]);
}

// ---- elementwise phi + cast (Q) ----
__global__ __launch_bounds__(256) void phi_cast(const float* __restrict__ in,
    unsigned short* __restrict__ out, long n) {
  long i = (long)(blockIdx.x * blockDim.x + threadIdx.x) * 4;
  const long stride = (long)gridDim.x * blockDim.x * 4;
  for (; i < n; i += stride) {
    float4 v = *(const float4*)(in + i);
    ushort4 o;
    o.x = f2bf(phi_f(v.x)); o.y = f2bf(phi_f(v.y));
    o.z = f2bf(phi_f(v.z)); o.w = f2bf(phi_f(v.w));
    *(ushort4*)(out + i) = o;
  }
}

// ---- Ksum[b*DIM+d] = sum_n Kt[b][d][n] ----
__global__ __launch_bounds__(256) void ksum_kernel(const unsigned short* __restrict__ Kt,
    float* __restrict__ Ksum) {
  const int row  = blockIdx.x * 4 + (threadIdx.x >> 6);   // b*DIM + d
  const int lane = threadIdx.x & 63;
  const unsigned short* p = Kt + (size_t)row * SEQ;
  float s = 0.f;
  #pragma unroll
  for (int c = 0; c < SEQ / 512; ++c) {
    u16x8 v = *(const u16x8*)(p + c * 512 + lane * 8);
    #pragma unroll
    for (int j = 0; j < 8; ++j) s += bf2f(v[j]);
  }
  #pragma unroll
  for (int off = 32; off > 0; off >>= 1) s += __shfl_down(s, off);
  if (lane == 0) Ksum[row] = s;
}

// ---- invZ[b*SEQ+n] = 1/(phiQ[n,:].Ksum[b,:] + eps) ----
__global__ __launch_bounds__(256) void z_kernel(const unsigned short* __restrict__ Qp,
    const float* __restrict__ Ksum, float* __restrict__ invZ) {
  const int row  = blockIdx.x * 4 + (threadIdx.x >> 6);   // b*SEQ + n
  const int lane = threadIdx.x & 63;
  const int b = row >> 12;                                 // /SEQ
  const unsigned short* q = Qp + (size_t)row * DIM;
  const float* ks = Ksum + b * DIM;
  float s = 0.f;
  #pragma unroll
  for (int c = 0; c < DIM / 512; ++c) {
    const int d0 = c * 512 + lane * 8;
    u16x8 v = *(const u16x8*)(q + d0);
    float4 k0 = *(const float4*)(ks + d0);
    float4 k1 = *(const float4*)(ks + d0 + 4);
    s += bf2f(v[0])*k0.x + bf2f(v[1])*k0.y + bf2f(v[2])*k0.z + bf2f(v[3])*k0.w
       + bf2f(v[4])*k1.x + bf2f(v[5])*k1.y + bf2f(v[6])*k1.z + bf2f(v[7])*k1.w;
  }
  #pragma unroll
  for (int off = 32; off > 0; off >>= 1) s += __shfl_down(s, off);
  if (lane == 0) invZ[row] = 1.0f / (s + EPS_F);
}

// ---- bt-GEMM: C[M][Nc] = A[M][K] * Bm[Nc][K]^T, bf16 in, m97 structure ----
// EPI==0: bf16 store. EPI==1: fp32 store scaled by invZ[row].
template<int EPI>
__global__ __launch_bounds__(256) void gemm_bt(const unsigned short* __restrict__ A,
    const unsigned short* __restrict__ Bm, void* __restrict__ Cv,
    const float* __restrict__ invZ, int M, int Nc, int K) {
  __shared__ unsigned short As[128 * 32];
  __shared__ unsigned short Bs[128 * 32];
  const int tid  = threadIdx.x;
  const int wid  = tid >> 6;
  const int lane = tid & 63;
  const int brow = blockIdx.y * 128;
  const int bcol = blockIdx.x * 128;
  const size_t batch = blockIdx.z;
  const unsigned short* Ab = A + batch * ((size_t)M * K) + (size_t)brow * K;
  const unsigned short* Bb = Bm + batch * ((size_t)Nc * K) + (size_t)bcol * K;

  const int srow = wid * 16 + (lane >> 2);     // staged row within 64-row half
  const int scol = (lane & 3) * 8;             // staged col (8 bf16 = 16B)
  const unsigned short* gA = Ab + (size_t)srow * K + scol;
  const unsigned short* gB = Bb + (size_t)srow * K + scol;

  const int wr = (wid >> 1) * 64;              // wave row offset in tile
  const int wc = (wid & 1) * 64;               // wave col offset in tile
  const int fr = lane & 15;
  const int fk = (lane >> 4) * 8;

  f32x4 acc[4][4] = {};

  for (int k0 = 0; k0 < K; k0 += 32) {
    #pragma unroll
    for (int i = 0; i < 2; ++i) {
      __builtin_amdgcn_global_load_lds(
          (const __attribute__((address_space(1))) unsigned int*)(gA + (size_t)i * 64 * K + k0),
          (__attribute__((address_space(3))) unsigned int*)(As + (i * 64 + wid * 16) * 32),
          16, 0, 0);
      __builtin_amdgcn_global_load_lds(
          (const __attribute__((address_space(1))) unsigned int*)(gB + (size_t)i * 64 * K + k0),
          (__attribute__((address_space(3))) unsigned int*)(Bs + (i * 64 + wid * 16) * 32),
          16, 0, 0);
    }
    __syncthreads();   // drains vmcnt -> LDS tiles valid
    bf16x8 af[4], bfrag[4];
    #pragma unroll
    for (int m = 0; m < 4; ++m)
      af[m] = *(const bf16x8*)(As + (wr + m * 16 + fr) * 32 + fk);
    #pragma unroll
    for (int n = 0; n < 4; ++n)
      bfrag[n] = *(const bf16x8*)(Bs + (wc + n * 16 + fr) * 32 + fk);
    #pragma unroll
    for (int m = 0; m < 4; ++m)
      #pragma unroll
      for (int n = 0; n < 4; ++n)
        acc[m][n] = __builtin_amdgcn_mfma_f32_16x16x32_bf16(af[m], bfrag[n], acc[m][n], 0, 0, 0);
    __syncthreads();   // all reads done before next overwrite
  }

  const int r0 = (lane >> 4) * 4;
  if (EPI == 0) {
    unsigned short* Cb = (unsigned short*)Cv + batch * ((size_t)M * Nc);
    #pragma unroll
    for (int m = 0; m < 4; ++m)
      #pragma unroll
      for (int n = 0; n < 4; ++n)
        #pragma unroll
        for (int r = 0; r < 4; ++r) {
          const int row = brow + wr + m * 16 + r0 + r;
          const int col = bcol + wc + n * 16 + fr;
          Cb[(size_t)row * Nc + col] = f2bf(acc[m][n][r]);
        }
  } else {
    float* Cb = (float*)Cv + batch * ((size_t)M * Nc);
    const float* zb = invZ + batch * (size_t)M;
    #pragma unroll
    for (int m = 0; m < 4; ++m)
      #pragma unroll
      for (int r = 0; r < 4; ++r) {
        const int row = brow + wr + m * 16 + r0 + r;
        const float z = zb[row];
        #pragma unroll
        for (int n = 0; n < 4; ++n) {
          const int col = bcol + wc + n * 16 + fr;
          Cb[(size_t)row * Nc + col] = acc[m][n][r] * z;
        }
      }
  }
}

extern "C" void kernel_launch(void* const* d_in, const int* in_sizes, int n_in,
                              void* d_out, int out_size, void* d_ws, size_t ws_size,
                              hipStream_t stream) {
  const float* Q = (const float*)d_in[0];
  const float* K = (const float*)d_in[1];
  const float* V = (const float*)d_in[2];
  float* out = (float*)d_out;

  char* ws = (char*)d_ws;
  size_t off = 0;
  auto alloc = [&](size_t bytes) {
    void* p = ws + off;
    off += (bytes + 255) & ~(size_t)255;
    return p;
  };
  unsigned short* Qp   = (unsigned short*)alloc((size_t)BATCH * SEQ * DIM * 2);
  unsigned short* Kt   = (unsigned short*)alloc((size_t)BATCH * SEQ * DIM * 2);
  unsigned short* Vt   = (unsigned short*)alloc((size_t)BATCH * SEQ * DIM * 2);
  unsigned short* KVt  = (unsigned short*)alloc((size_t)BATCH * DIM * DIM * 2);
  float* Ksum = (float*)alloc((size_t)BATCH * DIM * 4);
  float* invZ = (float*)alloc((size_t)BATCH * SEQ * 4);

  const dim3 tb(32, 8);
  // phi(K)^T and V^T (bf16, K-contiguous operands for bt-GEMM)
  phi_transpose<true ><<<dim3(DIM / 32, SEQ / 32, BATCH), tb, 0, stream>>>(K, Kt, SEQ, DIM);
  phi_transpose<false><<<dim3(DIM / 32, SEQ / 32, BATCH), tb, 0, stream>>>(V, Vt, SEQ, DIM);
  // phi(Q) (bf16, row-major: K-contiguous for pass 2)
  phi_cast<<<1024, 256, 0, stream>>>(Q, Qp, (long)BATCH * SEQ * DIM);
  // Ksum rows of Kt
  ksum_kernel<<<BATCH * DIM / 4, 256, 0, stream>>>(Kt, Ksum);
  // invZ
  z_kernel<<<BATCH * SEQ / 4, 256, 0, stream>>>(Qp, Ksum, invZ);
  // KVt[e][d] = sum_n Vt[e][n] * Kt[d][n]   (M=E, Nc=D, K=SEQ)
  gemm_bt<0><<<dim3(DIM / 128, DIM / 128, BATCH), 256, 0, stream>>>(
      Vt, Kt, KVt, nullptr, DIM, DIM, SEQ);
  // out[n][e] = (sum_d Qp[n][d] * KVt[e][d]) * invZ[n]   (M=SEQ, Nc=E, K=DIM)
  gemm_bt<1><<<dim3(DIM / 128, SEQ / 128, BATCH), 256, 0, stream>>>(
      Qp, KVt, out, invZ, SEQ, DIM, DIM);
}

// Round 2
// 210.719 us; speedup vs baseline: 1.0777x; 1.0777x over previous
//
#include <hip/hip_runtime.h>

#define BATCH 4
#define SEQ   4096
#define DIM   1024
#define EPS_F 1e-6f
#define KSPLIT 4

typedef __bf16 bf16_t;
typedef bf16_t bf16x8 __attribute__((ext_vector_type(8)));
typedef float  f32x4  __attribute__((ext_vector_type(4)));
typedef unsigned short u16x8 __attribute__((ext_vector_type(8)));

__device__ __forceinline__ unsigned short f2bf(float f) {
  unsigned u = __float_as_uint(f);
  u += 0x7FFFu + ((u >> 16) & 1u);          // round-to-nearest-even
  return (unsigned short)(u >> 16);
}
__device__ __forceinline__ float bf2f(unsigned short h) {
  return __uint_as_float(((unsigned)h) << 16);
}
__device__ __forceinline__ float phi_f(float x) {
  return x > 0.f ? x + 1.f : __expf(x);     // elu(x)+1
}

// ---- transpose (+ optional phi) fp32 [rows][cols] -> bf16 [cols][rows] ----
template<bool PHI>
__global__ __launch_bounds__(256) void phi_transpose(const float* __restrict__ in,
    unsigned short* __restrict__ out, int rows, int cols) {
  __shared__ float t[32][33];
  const int bx = blockIdx.x * 32;          // col base
  const int by = blockIdx.y * 32;          // row base
  const size_t bo = (size_t)blockIdx.z * rows * cols;
  const int x = threadIdx.x, y = threadIdx.y;
  #pragma unroll
  for (int j = 0; j < 32; j += 8) {
    float v = in[bo + (size_t)(by + y + j) * cols + bx + x];
    if (PHI) v = phi_f(v);
    t[y + j][x] = v;
  }
  __syncthreads();
  #pragma unroll
  for (int j = 0; j < 32; j += 8)
    out[bo + (size_t)(bx + y + j) * rows + by + x] = f2bf(t[x][y + j]);
}

// ---- elementwise phi + cast (Q) ----
__global__ __launch_bounds__(256) void phi_cast(const float* __restrict__ in,
    unsigned short* __restrict__ out, long n) {
  long i = (long)(blockIdx.x * blockDim.x + threadIdx.x) * 4;
  const long stride = (long)gridDim.x * blockDim.x * 4;
  for (; i < n; i += stride) {
    float4 v = *(const float4*)(in + i);
    ushort4 o;
    o.x = f2bf(phi_f(v.x)); o.y = f2bf(phi_f(v.y));
    o.z = f2bf(phi_f(v.z)); o.w = f2bf(phi_f(v.w));
    *(ushort4*)(out + i) = o;
  }
}

// ---- Ksum[b*DIM+d] = sum_n Kt[b][d][n] ----
__global__ __launch_bounds__(256) void ksum_kernel(const unsigned short* __restrict__ Kt,
    float* __restrict__ Ksum) {
  const int row  = blockIdx.x * 4 + (threadIdx.x >> 6);   // b*DIM + d
  const int lane = threadIdx.x & 63;
  const unsigned short* p = Kt + (size_t)row * SEQ;
  float s = 0.f;
  #pragma unroll
  for (int c = 0; c < SEQ / 512; ++c) {
    u16x8 v = *(const u16x8*)(p + c * 512 + lane * 8);
    #pragma unroll
    for (int j = 0; j < 8; ++j) s += bf2f(v[j]);
  }
  #pragma unroll
  for (int off = 32; off > 0; off >>= 1) s += __shfl_down(s, off);
  if (lane == 0) Ksum[row] = s;
}

// ---- invZ[b*SEQ+n] = 1/(phiQ[n,:].Ksum[b,:] + eps) ----
__global__ __launch_bounds__(256) void z_kernel(const unsigned short* __restrict__ Qp,
    const float* __restrict__ Ksum, float* __restrict__ invZ) {
  const int row  = blockIdx.x * 4 + (threadIdx.x >> 6);   // b*SEQ + n
  const int lane = threadIdx.x & 63;
  const int b = row >> 12;                                 // /SEQ
  const unsigned short* q = Qp + (size_t)row * DIM;
  const float* ks = Ksum + b * DIM;
  float s = 0.f;
  #pragma unroll
  for (int c = 0; c < DIM / 512; ++c) {
    const int d0 = c * 512 + lane * 8;
    u16x8 v = *(const u16x8*)(q + d0);
    float4 k0 = *(const float4*)(ks + d0);
    float4 k1 = *(const float4*)(ks + d0 + 4);
    s += bf2f(v[0])*k0.x + bf2f(v[1])*k0.y + bf2f(v[2])*k0.z + bf2f(v[3])*k0.w
       + bf2f(v[4])*k1.x + bf2f(v[5])*k1.y + bf2f(v[6])*k1.z + bf2f(v[7])*k1.w;
  }
  #pragma unroll
  for (int off = 32; off > 0; off >>= 1) s += __shfl_down(s, off);
  if (lane == 0) invZ[row] = 1.0f / (s + EPS_F);
}

// ---- reduce KSPLIT bf16 partials -> bf16 KVt ----
__global__ __launch_bounds__(256) void reduce_kv(const unsigned short* __restrict__ P,
    unsigned short* __restrict__ KVt) {
  const size_t per = (size_t)DIM * DIM;
  const size_t i = ((size_t)blockIdx.x * 256 + threadIdx.x) * 8;
  const size_t b = blockIdx.y;
  const unsigned short* p = P + b * KSPLIT * per + i;
  float s[8] = {};
  #pragma unroll
  for (int sp = 0; sp < KSPLIT; ++sp) {
    u16x8 v = *(const u16x8*)(p + sp * per);
    #pragma unroll
    for (int j = 0; j < 8; ++j) s[j] += bf2f(v[j]);
  }
  u16x8 o;
  #pragma unroll
  for (int j = 0; j < 8; ++j) o[j] = f2bf(s[j]);
  *(u16x8*)(KVt + b * per + i) = o;
}

// ---- bt-GEMM: C[M][Nc] = A[M][K] * Bm[Nc][K]^T, bf16 in, m97 structure ----
// EPI==0: bf16 store, split-K partials (z = batch*KS + split, C at z*M*Nc).
// EPI==1: fp32 store scaled by invZ[row], KS must be 1.
// LDS chunk swizzle: slot (row, c') holds global 16B-chunk c' ^ ((row>>1)&3).
template<int EPI, int KS>
__global__ __launch_bounds__(256) void gemm_bt(const unsigned short* __restrict__ A,
    const unsigned short* __restrict__ Bm, void* __restrict__ Cv,
    const float* __restrict__ invZ, int M, int Nc, int K) {
  __shared__ unsigned short As[128 * 32];
  __shared__ unsigned short Bs[128 * 32];
  const int tid  = threadIdx.x;
  const int wid  = tid >> 6;
  const int lane = tid & 63;
  const int brow = blockIdx.y * 128;
  const int bcol = blockIdx.x * 128;
  const int bz   = blockIdx.z;
  const size_t batch = bz / KS;
  const int split = bz % KS;
  const int Kc = K / KS;
  const int kbeg = split * Kc;
  const unsigned short* Ab = A + batch * ((size_t)M * K) + (size_t)brow * K;
  const unsigned short* Bb = Bm + batch * ((size_t)Nc * K) + (size_t)bcol * K;

  // staging: lane l -> LDS slot row (l>>2), chunk c'=(l&3); global chunk pre-swizzled
  const int srow  = wid * 16 + (lane >> 2);
  const int c_src = (lane & 3) ^ ((lane >> 3) & 3);     // = c' ^ ((row>>1)&3)
  const unsigned short* gA = Ab + (size_t)srow * K + c_src * 8;
  const unsigned short* gB = Bb + (size_t)srow * K + c_src * 8;

  const int wr = (wid >> 1) * 64;              // wave row offset in tile
  const int wc = (wid & 1) * 64;               // wave col offset in tile
  const int fr = lane & 15;
  const int c_rd = lane >> 4;                  // which 16B chunk of the 32-k slice
  const int sx = (fr >> 1) & 3;                // row-dependent swizzle term

  f32x4 acc[4][4] = {};

  for (int kc = 0; kc < Kc; kc += 32) {
    const int k0 = kbeg + kc;
    #pragma unroll
    for (int i = 0; i < 2; ++i) {
      __builtin_amdgcn_global_load_lds(
          (const __attribute__((address_space(1))) unsigned int*)(gA + (size_t)i * 64 * K + k0),
          (__attribute__((address_space(3))) unsigned int*)(As + (i * 64 + wid * 16) * 32),
          16, 0, 0);
      __builtin_amdgcn_global_load_lds(
          (const __attribute__((address_space(1))) unsigned int*)(gB + (size_t)i * 64 * K + k0),
          (__attribute__((address_space(3))) unsigned int*)(Bs + (i * 64 + wid * 16) * 32),
          16, 0, 0);
    }
    __syncthreads();   // drains vmcnt -> LDS tiles valid
    bf16x8 af[4], bfrag[4];
    #pragma unroll
    for (int m = 0; m < 4; ++m)
      af[m] = *(const bf16x8*)(As + (wr + m * 16 + fr) * 32 + ((c_rd ^ sx) << 3));
    #pragma unroll
    for (int n = 0; n < 4; ++n)
      bfrag[n] = *(const bf16x8*)(Bs + (wc + n * 16 + fr) * 32 + ((c_rd ^ sx) << 3));
    #pragma unroll
    for (int m = 0; m < 4; ++m)
      #pragma unroll
      for (int n = 0; n < 4; ++n)
        acc[m][n] = __builtin_amdgcn_mfma_f32_16x16x32_bf16(af[m], bfrag[n], acc[m][n], 0, 0, 0);
    __syncthreads();   // all reads done before next overwrite
  }

  const int r0 = (lane >> 4) * 4;
  if (EPI == 0) {
    unsigned short* Cb = (unsigned short*)Cv + (size_t)bz * M * Nc;
    #pragma unroll
    for (int m = 0; m < 4; ++m)
      #pragma unroll
      for (int n = 0; n < 4; ++n)
        #pragma unroll
        for (int r = 0; r < 4; ++r) {
          const int row = brow + wr + m * 16 + r0 + r;
          const int col = bcol + wc + n * 16 + fr;
          Cb[(size_t)row * Nc + col] = f2bf(acc[m][n][r]);
        }
  } else {
    float* Cb = (float*)Cv + batch * ((size_t)M * Nc);
    const float* zb = invZ + batch * (size_t)M;
    #pragma unroll
    for (int m = 0; m < 4; ++m)
      #pragma unroll
      for (int r = 0; r < 4; ++r) {
        const int row = brow + wr + m * 16 + r0 + r;
        const float z = zb[row];
        #pragma unroll
        for (int n = 0; n < 4; ++n) {
          const int col = bcol + wc + n * 16 + fr;
          Cb[(size_t)row * Nc + col] = acc[m][n][r] * z;
        }
      }
  }
}

extern "C" void kernel_launch(void* const* d_in, const int* in_sizes, int n_in,
                              void* d_out, int out_size, void* d_ws, size_t ws_size,
                              hipStream_t stream) {
  const float* Q = (const float*)d_in[0];
  const float* K = (const float*)d_in[1];
  const float* V = (const float*)d_in[2];
  float* out = (float*)d_out;

  char* ws = (char*)d_ws;
  size_t off = 0;
  auto alloc = [&](size_t bytes) {
    void* p = ws + off;
    off += (bytes + 255) & ~(size_t)255;
    return p;
  };
  // Qp region doubles as split-K partial buffer P (both 32 MB).
  // Order: gemm1 writes P -> reduce reads P -> phi_cast overwrites as Qp.
  unsigned short* Qp   = (unsigned short*)alloc((size_t)BATCH * SEQ * DIM * 2);
  unsigned short* P    = Qp;  // [B][KSPLIT][DIM*DIM] bf16 = 32 MB
  unsigned short* Kt   = (unsigned short*)alloc((size_t)BATCH * SEQ * DIM * 2);
  unsigned short* Vt   = (unsigned short*)alloc((size_t)BATCH * SEQ * DIM * 2);
  unsigned short* KVt  = (unsigned short*)alloc((size_t)BATCH * DIM * DIM * 2);
  float* Ksum = (float*)alloc((size_t)BATCH * DIM * 4);
  float* invZ = (float*)alloc((size_t)BATCH * SEQ * 4);

  const dim3 tb(32, 8);
  // phi(K)^T and V^T (bf16, K-contiguous operands for bt-GEMM)
  phi_transpose<true ><<<dim3(DIM / 32, SEQ / 32, BATCH), tb, 0, stream>>>(K, Kt, SEQ, DIM);
  phi_transpose<false><<<dim3(DIM / 32, SEQ / 32, BATCH), tb, 0, stream>>>(V, Vt, SEQ, DIM);
  // Ksum rows of Kt
  ksum_kernel<<<BATCH * DIM / 4, 256, 0, stream>>>(Kt, Ksum);
  // gemm1 split-K: P[b][s][e][d] = sum_{n in split s} Vt[e][n] * Kt[d][n]
  gemm_bt<0, KSPLIT><<<dim3(DIM / 128, DIM / 128, BATCH * KSPLIT), 256, 0, stream>>>(
      Vt, Kt, P, nullptr, DIM, DIM, SEQ);
  // KVt = sum_s P[s]
  reduce_kv<<<dim3(DIM * DIM / (256 * 8), BATCH), 256, 0, stream>>>(P, KVt);
  // phi(Q) (bf16, row-major) -- AFTER reduce: overwrites P region
  phi_cast<<<1024, 256, 0, stream>>>(Q, Qp, (long)BATCH * SEQ * DIM);
  // invZ
  z_kernel<<<BATCH * SEQ / 4, 256, 0, stream>>>(Qp, Ksum, invZ);
  // out[n][e] = (sum_d Qp[n][d] * KVt[e][d]) * invZ[n]   (M=SEQ, Nc=E, K=DIM)
  gemm_bt<1, 1><<<dim3(DIM / 128, SEQ / 128, BATCH), 256, 0, stream>>>(
      Qp, KVt, out, invZ, SEQ, DIM, DIM);
}

// Round 3
// 185.105 us; speedup vs baseline: 1.2268x; 1.1384x over previous
//
#include <hip/hip_runtime.h>

#define BATCH 4
#define SEQ   4096
#define DIM   1024
#define EPS_F 1e-6f
#define KSPLIT 4

typedef __bf16 bf16_t;
typedef bf16_t bf16x8 __attribute__((ext_vector_type(8)));
typedef float  f32x4  __attribute__((ext_vector_type(4)));
typedef unsigned short u16x8 __attribute__((ext_vector_type(8)));

__device__ __forceinline__ unsigned short f2bf(float f) {
  unsigned u = __float_as_uint(f);
  u += 0x7FFFu + ((u >> 16) & 1u);          // round-to-nearest-even
  return (unsigned short)(u >> 16);
}
__device__ __forceinline__ float bf2f(unsigned short h) {
  return __uint_as_float(((unsigned)h) << 16);
}
__device__ __forceinline__ float phi_f(float x) {
  return x > 0.f ? x + 1.f : __expf(x);     // elu(x)+1
}

__global__ __launch_bounds__(256) void zero_f32(float* __restrict__ p, int n) {
  const int i = blockIdx.x * 256 + threadIdx.x;
  if (i < n) p[i] = 0.f;
}

// ---- transpose (+ optional phi, optional fused column-sum) ----
// in fp32 [rows][cols] -> out bf16 [cols][rows]; ksum[b][col] += sum_rows phi(in)
template<bool PHI, bool KSUM>
__global__ __launch_bounds__(256) void phi_transpose(const float* __restrict__ in,
    unsigned short* __restrict__ out, float* __restrict__ ksum, int rows, int cols) {
  __shared__ float t[32][33];
  __shared__ float ps[8][32];
  const int bx = blockIdx.x * 32;          // col base
  const int by = blockIdx.y * 32;          // row base
  const size_t bo = (size_t)blockIdx.z * rows * cols;
  const int x = threadIdx.x, y = threadIdx.y;
  #pragma unroll
  for (int j = 0; j < 32; j += 8) {
    float v = in[bo + (size_t)(by + y + j) * cols + bx + x];
    if (PHI) v = phi_f(v);
    t[y + j][x] = v;
  }
  __syncthreads();
  #pragma unroll
  for (int j = 0; j < 32; j += 8)
    out[bo + (size_t)(bx + y + j) * rows + by + x] = f2bf(t[x][y + j]);
  if (KSUM) {
    float s = t[y][x] + t[y + 8][x] + t[y + 16][x] + t[y + 24][x];
    ps[y][x] = s;
    __syncthreads();
    if (y == 0) {
      float tot = 0.f;
      #pragma unroll
      for (int j = 0; j < 8; ++j) tot += ps[j][x];
      atomicAdd(&ksum[(size_t)blockIdx.z * cols + bx + x], tot);
    }
  }
}

// ---- phi(Q) cast + fused Z: invZ[row] = 1/(sum_d bf16(phi(Q[row][d]))*Ksum[d] + eps)
__global__ __launch_bounds__(256) void phi_cast_qz(const float* __restrict__ Q,
    const float* __restrict__ Ksum, unsigned short* __restrict__ Qp,
    float* __restrict__ invZ) {
  const int row  = blockIdx.x * 4 + (threadIdx.x >> 6);   // b*SEQ + n
  const int lane = threadIdx.x & 63;
  const int b = row >> 12;                                 // /SEQ
  const float* q  = Q + (size_t)row * DIM;
  const float* ks = Ksum + (size_t)b * DIM;
  float s = 0.f;
  #pragma unroll
  for (int c = 0; c < 2; ++c) {
    const int d0 = c * 512 + lane * 8;
    float4 v0 = *(const float4*)(q + d0);
    float4 v1 = *(const float4*)(q + d0 + 4);
    float4 k0 = *(const float4*)(ks + d0);
    float4 k1 = *(const float4*)(ks + d0 + 4);
    u16x8 o;
    o[0] = f2bf(phi_f(v0.x)); s += bf2f(o[0]) * k0.x;
    o[1] = f2bf(phi_f(v0.y)); s += bf2f(o[1]) * k0.y;
    o[2] = f2bf(phi_f(v0.z)); s += bf2f(o[2]) * k0.z;
    o[3] = f2bf(phi_f(v0.w)); s += bf2f(o[3]) * k0.w;
    o[4] = f2bf(phi_f(v1.x)); s += bf2f(o[4]) * k1.x;
    o[5] = f2bf(phi_f(v1.y)); s += bf2f(o[5]) * k1.y;
    o[6] = f2bf(phi_f(v1.z)); s += bf2f(o[6]) * k1.z;
    o[7] = f2bf(phi_f(v1.w)); s += bf2f(o[7]) * k1.w;
    *(u16x8*)(Qp + (size_t)row * DIM + d0) = o;
  }
  #pragma unroll
  for (int off = 32; off > 0; off >>= 1) s += __shfl_down(s, off);
  if (lane == 0) invZ[row] = 1.0f / (s + EPS_F);
}

// ---- reduce KSPLIT bf16 partials -> bf16 KVt ----
__global__ __launch_bounds__(256) void reduce_kv(const unsigned short* __restrict__ P,
    unsigned short* __restrict__ KVt) {
  const size_t per = (size_t)DIM * DIM;
  const size_t i = ((size_t)blockIdx.x * 256 + threadIdx.x) * 8;
  const size_t b = blockIdx.y;
  const unsigned short* p = P + b * KSPLIT * per + i;
  float s[8] = {};
  #pragma unroll
  for (int sp = 0; sp < KSPLIT; ++sp) {
    u16x8 v = *(const u16x8*)(p + sp * per);
    #pragma unroll
    for (int j = 0; j < 8; ++j) s[j] += bf2f(v[j]);
  }
  u16x8 o;
  #pragma unroll
  for (int j = 0; j < 8; ++j) o[j] = f2bf(s[j]);
  *(u16x8*)(KVt + b * per + i) = o;
}

// ---- bt-GEMM: C[M][Nc] = A[M][K] * Bm[Nc][K]^T, bf16, 2-phase dbuf ----
// 1D grid (XCD-chunk swizzled), logical (bx,by,bz) with x fastest.
// EPI==0: bf16 store, split-K partials (bz = batch*KS + split).
// EPI==1: fp32 store scaled by invZ[row], KS must be 1.
// LDS chunk swizzle: slot (row, c') holds global 16B-chunk c' ^ ((row>>1)&3).
template<int EPI, int KS>
__global__ __launch_bounds__(256) void gemm_bt(const unsigned short* __restrict__ A,
    const unsigned short* __restrict__ Bm, void* __restrict__ Cv,
    const float* __restrict__ invZ, int M, int Nc, int K, int gx, int gy) {
  __shared__ unsigned short As[2][128 * 32];
  __shared__ unsigned short Bs[2][128 * 32];
  const int tid  = threadIdx.x;
  const int wid  = tid >> 6;
  const int lane = tid & 63;
  // XCD-chunked bijective swizzle (gridDim.x divisible by 8)
  const int nwg = gridDim.x;
  const int id  = blockIdx.x;
  const int sw  = (id & 7) * (nwg >> 3) + (id >> 3);
  const int bxi = sw % gx;
  const int byi = (sw / gx) % gy;
  const int bz  = sw / (gx * gy);
  const int brow = byi * 128;
  const int bcol = bxi * 128;
  const size_t batch = bz / KS;
  const int split = bz % KS;
  const int Kc = K / KS;
  const int kbeg = split * Kc;
  const unsigned short* Ab = A + batch * ((size_t)M * K) + (size_t)brow * K;
  const unsigned short* Bb = Bm + batch * ((size_t)Nc * K) + (size_t)bcol * K;

  // staging: lane l -> LDS slot row (l>>2), chunk c'=(l&3); global chunk pre-swizzled
  const int srow  = wid * 16 + (lane >> 2);
  const int c_src = (lane & 3) ^ ((lane >> 3) & 3);     // = c' ^ ((row>>1)&3)
  const unsigned short* gA = Ab + (size_t)srow * K + c_src * 8;
  const unsigned short* gB = Bb + (size_t)srow * K + c_src * 8;

  const int wr = (wid >> 1) * 64;              // wave row offset in tile
  const int wc = (wid & 1) * 64;               // wave col offset in tile
  const int fr = lane & 15;
  const int rdoff = (((lane >> 4) ^ ((lane >> 1) & 3)) << 3);  // swizzled k-chunk read offset

  f32x4 acc[4][4] = {};

  auto STAGE = [&](int buf, int k0) {
    #pragma unroll
    for (int i = 0; i < 2; ++i) {
      __builtin_amdgcn_global_load_lds(
          (const __attribute__((address_space(1))) unsigned int*)(gA + (size_t)i * 64 * K + k0),
          (__attribute__((address_space(3))) unsigned int*)(&As[buf][(i * 64 + wid * 16) * 32]),
          16, 0, 0);
      __builtin_amdgcn_global_load_lds(
          (const __attribute__((address_space(1))) unsigned int*)(gB + (size_t)i * 64 * K + k0),
          (__attribute__((address_space(3))) unsigned int*)(&Bs[buf][(i * 64 + wid * 16) * 32]),
          16, 0, 0);
    }
  };
  auto COMPUTE = [&](int buf) {
    bf16x8 af[4], bfr[4];
    #pragma unroll
    for (int m = 0; m < 4; ++m)
      af[m] = *(const bf16x8*)(&As[buf][(wr + m * 16 + fr) * 32 + rdoff]);
    #pragma unroll
    for (int n = 0; n < 4; ++n)
      bfr[n] = *(const bf16x8*)(&Bs[buf][(wc + n * 16 + fr) * 32 + rdoff]);
    #pragma unroll
    for (int m = 0; m < 4; ++m)
      #pragma unroll
      for (int n = 0; n < 4; ++n)
        acc[m][n] = __builtin_amdgcn_mfma_f32_16x16x32_bf16(af[m], bfr[n], acc[m][n], 0, 0, 0);
  };

  // 2-phase: prefetch next tile before computing current; one barrier per step.
  STAGE(0, kbeg);
  __syncthreads();
  const int NT = Kc / 32;
  int cur = 0;
  for (int t = 0; t < NT - 1; ++t) {
    STAGE(cur ^ 1, kbeg + (t + 1) * 32);
    COMPUTE(cur);
    __syncthreads();   // drains this wave's prefetch (vmcnt) + all reads of cur
    cur ^= 1;
  }
  COMPUTE(cur);

  const int r0 = (lane >> 4) * 4;
  if (EPI == 0) {
    unsigned short* Cb = (unsigned short*)Cv + (size_t)bz * M * Nc;
    #pragma unroll
    for (int m = 0; m < 4; ++m)
      #pragma unroll
      for (int n = 0; n < 4; ++n)
        #pragma unroll
        for (int r = 0; r < 4; ++r) {
          const int row = brow + wr + m * 16 + r0 + r;
          const int col = bcol + wc + n * 16 + fr;
          Cb[(size_t)row * Nc + col] = f2bf(acc[m][n][r]);
        }
  } else {
    float* Cb = (float*)Cv + batch * ((size_t)M * Nc);
    const float* zb = invZ + batch * (size_t)M;
    #pragma unroll
    for (int m = 0; m < 4; ++m)
      #pragma unroll
      for (int r = 0; r < 4; ++r) {
        const int row = brow + wr + m * 16 + r0 + r;
        const float z = zb[row];
        #pragma unroll
        for (int n = 0; n < 4; ++n) {
          const int col = bcol + wc + n * 16 + fr;
          Cb[(size_t)row * Nc + col] = acc[m][n][r] * z;
        }
      }
  }
}

extern "C" void kernel_launch(void* const* d_in, const int* in_sizes, int n_in,
                              void* d_out, int out_size, void* d_ws, size_t ws_size,
                              hipStream_t stream) {
  const float* Q = (const float*)d_in[0];
  const float* K = (const float*)d_in[1];
  const float* V = (const float*)d_in[2];
  float* out = (float*)d_out;

  char* ws = (char*)d_ws;
  size_t off = 0;
  auto alloc = [&](size_t bytes) {
    void* p = ws + off;
    off += (bytes + 255) & ~(size_t)255;
    return p;
  };
  // Qp region doubles as split-K partial buffer P (both 32 MB).
  unsigned short* Qp   = (unsigned short*)alloc((size_t)BATCH * SEQ * DIM * 2);
  unsigned short* P    = Qp;  // [B][KSPLIT][DIM*DIM] bf16 = 32 MB
  unsigned short* Kt   = (unsigned short*)alloc((size_t)BATCH * SEQ * DIM * 2);
  unsigned short* Vt   = (unsigned short*)alloc((size_t)BATCH * SEQ * DIM * 2);
  unsigned short* KVt  = (unsigned short*)alloc((size_t)BATCH * DIM * DIM * 2);
  float* Ksum = (float*)alloc((size_t)BATCH * DIM * 4);
  float* invZ = (float*)alloc((size_t)BATCH * SEQ * 4);

  const dim3 tb(32, 8);
  // Ksum = 0, then phi(K)^T with fused column-sum; V^T plain.
  zero_f32<<<(BATCH * DIM + 255) / 256, 256, 0, stream>>>(Ksum, BATCH * DIM);
  phi_transpose<true, true ><<<dim3(DIM / 32, SEQ / 32, BATCH), tb, 0, stream>>>(K, Kt, Ksum, SEQ, DIM);
  phi_transpose<false, false><<<dim3(DIM / 32, SEQ / 32, BATCH), tb, 0, stream>>>(V, Vt, nullptr, SEQ, DIM);
  // gemm1 split-K: P[b][s][e][d] = sum_{n in split s} Vt[e][n] * Kt[d][n]
  gemm_bt<0, KSPLIT><<<(DIM / 128) * (DIM / 128) * BATCH * KSPLIT, 256, 0, stream>>>(
      Vt, Kt, P, nullptr, DIM, DIM, SEQ, DIM / 128, DIM / 128);
  // KVt = sum_s P[s]
  reduce_kv<<<dim3(DIM * DIM / (256 * 8), BATCH), 256, 0, stream>>>(P, KVt);
  // phi(Q) cast + fused Z  (AFTER reduce: overwrites P region)
  phi_cast_qz<<<BATCH * SEQ / 4, 256, 0, stream>>>(Q, Ksum, Qp, invZ);
  // out[n][e] = (sum_d Qp[n][d] * KVt[e][d]) * invZ[n]
  gemm_bt<1, 1><<<(DIM / 128) * (SEQ / 128) * BATCH, 256, 0, stream>>>(
      Qp, KVt, out, invZ, SEQ, DIM, DIM, DIM / 128, SEQ / 128);
}

// Round 4
// 146.436 us; speedup vs baseline: 1.5508x; 1.2641x over previous
//
#include <hip/hip_runtime.h>

#define BATCH 4
#define SEQ   4096
#define DIM   1024
#define EPS_F 1e-6f
#define KSPLIT 4

typedef __bf16 bf16_t;
typedef bf16_t bf16x8 __attribute__((ext_vector_type(8)));
typedef float  f32x4  __attribute__((ext_vector_type(4)));
typedef unsigned short u16x8 __attribute__((ext_vector_type(8)));

__device__ __forceinline__ unsigned short f2bf(float f) {
  unsigned u = __float_as_uint(f);
  u += 0x7FFFu + ((u >> 16) & 1u);          // round-to-nearest-even
  return (unsigned short)(u >> 16);
}
__device__ __forceinline__ float bf2f(unsigned short h) {
  return __uint_as_float(((unsigned)h) << 16);
}
__device__ __forceinline__ float phi_f(float x) {
  return x > 0.f ? x + 1.f : __expf(x);     // elu(x)+1
}

__global__ __launch_bounds__(256) void zero_f32(float* __restrict__ p, int n) {
  const int i = blockIdx.x * 256 + threadIdx.x;
  if (i < n) p[i] = 0.f;
}

// ---- transpose (+ optional phi, optional fused column-sum) ----
template<bool PHI, bool KSUM>
__global__ __launch_bounds__(256) void phi_transpose(const float* __restrict__ in,
    unsigned short* __restrict__ out, float* __restrict__ ksum, int rows, int cols) {
  __shared__ float t[32][33];
  __shared__ float ps[8][32];
  const int bx = blockIdx.x * 32;          // col base
  const int by = blockIdx.y * 32;          // row base
  const size_t bo = (size_t)blockIdx.z * rows * cols;
  const int x = threadIdx.x, y = threadIdx.y;
  #pragma unroll
  for (int j = 0; j < 32; j += 8) {
    float v = in[bo + (size_t)(by + y + j) * cols + bx + x];
    if (PHI) v = phi_f(v);
    t[y + j][x] = v;
  }
  __syncthreads();
  #pragma unroll
  for (int j = 0; j < 32; j += 8)
    out[bo + (size_t)(bx + y + j) * rows + by + x] = f2bf(t[x][y + j]);
  if (KSUM) {
    float s = t[y][x] + t[y + 8][x] + t[y + 16][x] + t[y + 24][x];
    ps[y][x] = s;
    __syncthreads();
    if (y == 0) {
      float tot = 0.f;
      #pragma unroll
      for (int j = 0; j < 8; ++j) tot += ps[j][x];
      atomicAdd(&ksum[(size_t)blockIdx.z * cols + bx + x], tot);
    }
  }
}

// ---- phi(Q) cast + fused Z ----
__global__ __launch_bounds__(256) void phi_cast_qz(const float* __restrict__ Q,
    const float* __restrict__ Ksum, unsigned short* __restrict__ Qp,
    float* __restrict__ invZ) {
  const int row  = blockIdx.x * 4 + (threadIdx.x >> 6);   // b*SEQ + n
  const int lane = threadIdx.x & 63;
  const int b = row >> 12;
  const float* q  = Q + (size_t)row * DIM;
  const float* ks = Ksum + (size_t)b * DIM;
  float s = 0.f;
  #pragma unroll
  for (int c = 0; c < 2; ++c) {
    const int d0 = c * 512 + lane * 8;
    float4 v0 = *(const float4*)(q + d0);
    float4 v1 = *(const float4*)(q + d0 + 4);
    float4 k0 = *(const float4*)(ks + d0);
    float4 k1 = *(const float4*)(ks + d0 + 4);
    u16x8 o;
    o[0] = f2bf(phi_f(v0.x)); s += bf2f(o[0]) * k0.x;
    o[1] = f2bf(phi_f(v0.y)); s += bf2f(o[1]) * k0.y;
    o[2] = f2bf(phi_f(v0.z)); s += bf2f(o[2]) * k0.z;
    o[3] = f2bf(phi_f(v0.w)); s += bf2f(o[3]) * k0.w;
    o[4] = f2bf(phi_f(v1.x)); s += bf2f(o[4]) * k1.x;
    o[5] = f2bf(phi_f(v1.y)); s += bf2f(o[5]) * k1.y;
    o[6] = f2bf(phi_f(v1.z)); s += bf2f(o[6]) * k1.z;
    o[7] = f2bf(phi_f(v1.w)); s += bf2f(o[7]) * k1.w;
    *(u16x8*)(Qp + (size_t)row * DIM + d0) = o;
  }
  #pragma unroll
  for (int off = 32; off > 0; off >>= 1) s += __shfl_down(s, off);
  if (lane == 0) invZ[row] = 1.0f / (s + EPS_F);
}

// ---- reduce KSPLIT bf16 partials -> bf16 KVt ----
__global__ __launch_bounds__(256) void reduce_kv(const unsigned short* __restrict__ P,
    unsigned short* __restrict__ KVt) {
  const size_t per = (size_t)DIM * DIM;
  const size_t i = ((size_t)blockIdx.x * 256 + threadIdx.x) * 8;
  const size_t b = blockIdx.y;
  const unsigned short* p = P + b * KSPLIT * per + i;
  float s[8] = {};
  #pragma unroll
  for (int sp = 0; sp < KSPLIT; ++sp) {
    u16x8 v = *(const u16x8*)(p + sp * per);
    #pragma unroll
    for (int j = 0; j < 8; ++j) s[j] += bf2f(v[j]);
  }
  u16x8 o;
  #pragma unroll
  for (int j = 0; j < 8; ++j) o[j] = f2bf(s[j]);
  *(u16x8*)(KVt + b * per + i) = o;
}

// ================= 256x256 8-phase bt-GEMM (T2+T3+T4+T5) =================
// C[M][Nc] = A[M][K] * Bm[Nc][K]^T, bf16 in. 512 thr = 8 waves (2M x 4N),
// BK=64, dbuf LDS 128KB. Counted vmcnt(6) at phases 4/8 only.
// LDS swizzle: slot(row, c) holds global chunk c ^ (row&7); read side applies
// the same XOR (chunk = kk*4+g ^ (fr&7)). global_load_lds dest stays linear.
// Half-tile staging sets match wave read-sets:
//   A.h : rows {0-63,128-191} (h=0) / {64-127,192-255} (h=1)
//   B.h : col stripes 64w+[h*32,(h+1)*32)
#define GLD(gp, lp) __builtin_amdgcn_global_load_lds( \
    (const __attribute__((address_space(1))) unsigned int*)(gp), \
    (__attribute__((address_space(3))) unsigned int*)(lp), 16, 0, 0)
#define BARRIER __builtin_amdgcn_s_barrier()
#define WAITV(n) asm volatile("s_waitcnt vmcnt(" #n ")" ::: "memory")

template<int EPI, int KS>
__global__ __launch_bounds__(512, 2) void gemm256_bt(
    const unsigned short* __restrict__ A, const unsigned short* __restrict__ Bm,
    void* __restrict__ Cv, const float* __restrict__ invZ,
    int M, int Nc, int K, int gx, int gy) {
  extern __shared__ unsigned short lds[];
  unsigned short* const As0 = lds;
  unsigned short* const As1 = lds + 16384;
  unsigned short* const Bs0 = lds + 32768;
  unsigned short* const Bs1 = lds + 49152;

  const int t    = threadIdx.x;
  const int wid  = t >> 6;
  const int lane = t & 63;
  // XCD-chunked bijective swizzle (gridDim.x divisible by 8)
  const int id   = blockIdx.x;
  const int sw   = (id & 7) * (gridDim.x >> 3) + (id >> 3);
  const int bxi  = sw % gx;
  const int rem  = sw / gx;
  const int byi  = rem % gy;
  const int bz   = rem / gy;
  const int brow = byi * 256, bcol = bxi * 256;
  const size_t batch = bz / KS;
  const int split = bz % KS;
  const int Kc = K / KS;
  const unsigned short* Ab = A + batch * ((size_t)M * K) + (size_t)brow * K + (size_t)split * Kc;
  const unsigned short* Bb = Bm + batch * ((size_t)Nc * K) + (size_t)bcol * K + (size_t)split * Kc;

  // staging: thread t -> row srow_t = t>>3, chunk c = t&7 (linear LDS dest);
  // global chunk pre-swizzled with (row&7).
  const int srow_t = t >> 3;                       // 0..63
  const int c_src  = (t & 7) ^ (srow_t & 7);
  const unsigned short* gA = Ab + (size_t)srow_t * K + c_src * 8;
  const unsigned short* gB = Bb + (size_t)((srow_t >> 5) * 64 + (srow_t & 31)) * K + c_src * 8;
  const int ldsAu = wid * 512;                          // wave-uniform LDS base (elems)
  const int ldsBu = wid * 512 + (wid >> 2) * 2048;

  auto stageA = [&](unsigned short* D, int h, int kt) {
    GLD(gA + (size_t)(h * 64) * K + (size_t)kt * 64,       D + (h * 64) * 64 + ldsAu);
    GLD(gA + (size_t)(128 + h * 64) * K + (size_t)kt * 64, D + (128 + h * 64) * 64 + ldsAu);
  };
  auto stageB = [&](unsigned short* D, int h, int kt) {
    GLD(gB + (size_t)(h * 32) * K + (size_t)kt * 64,       D + (h * 32) * 64 + ldsBu);
    GLD(gB + (size_t)(128 + h * 32) * K + (size_t)kt * 64, D + (128 + h * 32) * 64 + ldsBu);
  };

  const int fr  = lane & 15;
  const int g   = lane >> 4;
  const int wrw = (wid >> 2) * 128;          // wave row base (2 M-groups)
  const int wcw = (wid & 3) * 64;            // wave col base (4 N-groups)
  const int ck0 = ((g)     ^ (fr & 7)) * 8;  // kk=0 swizzled chunk (elems)
  const int ck1 = ((4 + g) ^ (fr & 7)) * 8;  // kk=1

  f32x4 acc[8][4] = {};
  bf16x8 af[4][2], bf0[2][2], bf1[2][2];

#define LOADA(S, mh) { _Pragma("unroll") for (int m_ = 0; m_ < 4; ++m_) { \
    const int ro_ = (wrw + ((mh) * 4 + m_) * 16 + fr) * 64; \
    af[m_][0] = *(const bf16x8*)((S) + ro_ + ck0); \
    af[m_][1] = *(const bf16x8*)((S) + ro_ + ck1); } }
#define LOADB(S, nh, BF) { _Pragma("unroll") for (int n_ = 0; n_ < 2; ++n_) { \
    const int ro_ = (wcw + (nh) * 32 + n_ * 16 + fr) * 64; \
    BF[n_][0] = *(const bf16x8*)((S) + ro_ + ck0); \
    BF[n_][1] = *(const bf16x8*)((S) + ro_ + ck1); } }
#define QUAD(mh, nh, BF) { __builtin_amdgcn_s_setprio(1); \
    _Pragma("unroll") for (int m_ = 0; m_ < 4; ++m_) \
    _Pragma("unroll") for (int n_ = 0; n_ < 2; ++n_) \
    _Pragma("unroll") for (int k_ = 0; k_ < 2; ++k_) \
      acc[(mh) * 4 + m_][(nh) * 2 + n_] = __builtin_amdgcn_mfma_f32_16x16x32_bf16( \
          af[m_][k_], BF[n_][k_], acc[(mh) * 4 + m_][(nh) * 2 + n_], 0, 0, 0); \
    __builtin_amdgcn_s_setprio(0); }

  // prologue: tile0 fully + tile1 {A.X,B.X,B.Y}; t1.A.Y staged in iter0 ph1
  stageA(As0, 0, 0); stageB(Bs0, 0, 0); stageB(Bs0, 1, 0); stageA(As0, 1, 0);
  stageA(As1, 0, 1); stageB(Bs1, 0, 1); stageB(Bs1, 1, 1);
  WAITV(6);
  BARRIER;

  const int NITER = Kc >> 7;                 // 2 K-tiles (2x64) per iteration
  for (int i = 0; i < NITER - 1; ++i) {
    const int k2 = 2 * i;
    // ph1: reads buf0 A.X,B.X | stages t(2i+1).A.Y
    LOADA(As0, 0); LOADB(Bs0, 0, bf0); stageA(As1, 1, k2 + 1);
    BARRIER; QUAD(0, 0, bf0); BARRIER;
    // ph2: reads buf0 B.Y | stages t(2i+2).A.X
    LOADB(Bs0, 1, bf1); stageA(As0, 0, k2 + 2);
    BARRIER; QUAD(0, 1, bf1); BARRIER;
    // ph3: reads buf0 A.Y | stages t(2i+2).B.X
    LOADA(As0, 1); stageB(Bs0, 0, k2 + 2);
    BARRIER; QUAD(1, 0, bf0); BARRIER;
    // ph4: stages t(2i+2).B.Y | drain tile 2i+1 (oldest 8), keep 6 in flight
    stageB(Bs0, 1, k2 + 2); WAITV(6);
    BARRIER; QUAD(1, 1, bf1); BARRIER;
    // ph5: reads buf1 A.X,B.X | stages t(2i+2).A.Y
    LOADA(As1, 0); LOADB(Bs1, 0, bf0); stageA(As0, 1, k2 + 2);
    BARRIER; QUAD(0, 0, bf0); BARRIER;
    // ph6: reads buf1 B.Y | stages t(2i+3).A.X
    LOADB(Bs1, 1, bf1); stageA(As1, 0, k2 + 3);
    BARRIER; QUAD(0, 1, bf1); BARRIER;
    // ph7: reads buf1 A.Y | stages t(2i+3).B.X
    LOADA(As1, 1); stageB(Bs1, 0, k2 + 3);
    BARRIER; QUAD(1, 0, bf0); BARRIER;
    // ph8: stages t(2i+3).B.Y | drain tile 2i+2
    stageB(Bs1, 1, k2 + 3); WAITV(6);
    BARRIER; QUAD(1, 1, bf1); BARRIER;
  }
  { // epilogue iteration: tiles NT-2, NT-1; only t(NT-1).A.Y still to stage
    const int k2 = 2 * (NITER - 1);
    LOADA(As0, 0); LOADB(Bs0, 0, bf0); stageA(As1, 1, k2 + 1);
    BARRIER; QUAD(0, 0, bf0); BARRIER;
    LOADB(Bs0, 1, bf1);
    BARRIER; QUAD(0, 1, bf1); BARRIER;
    LOADA(As0, 1);
    BARRIER; QUAD(1, 0, bf0); BARRIER;
    WAITV(0);
    BARRIER; QUAD(1, 1, bf1); BARRIER;
    LOADA(As1, 0); LOADB(Bs1, 0, bf0);
    BARRIER; QUAD(0, 0, bf0); BARRIER;
    LOADB(Bs1, 1, bf1);
    BARRIER; QUAD(0, 1, bf1); BARRIER;
    LOADA(As1, 1);
    BARRIER; QUAD(1, 0, bf0); BARRIER;
    QUAD(1, 1, bf1);
  }
#undef LOADA
#undef LOADB
#undef QUAD

  // epilogue: C/D layout col=fr, row=g*4+r per 16x16 fragment
  if (EPI == 0) {
    unsigned short* Cb = (unsigned short*)Cv + (size_t)bz * M * Nc;
    #pragma unroll
    for (int m = 0; m < 8; ++m) {
      const int row = brow + wrw + m * 16 + g * 4;
      #pragma unroll
      for (int r = 0; r < 4; ++r)
        #pragma unroll
        for (int n = 0; n < 4; ++n)
          Cb[(size_t)(row + r) * Nc + bcol + wcw + n * 16 + fr] = f2bf(acc[m][n][r]);
    }
  } else {
    float* Cb = (float*)Cv + batch * ((size_t)M * Nc);
    const float* zb = invZ + batch * (size_t)M;
    #pragma unroll
    for (int m = 0; m < 8; ++m) {
      const int row = brow + wrw + m * 16 + g * 4;
      #pragma unroll
      for (int r = 0; r < 4; ++r) {
        const float z = zb[row + r];
        #pragma unroll
        for (int n = 0; n < 4; ++n)
          Cb[(size_t)(row + r) * Nc + bcol + wcw + n * 16 + fr] = acc[m][n][r] * z;
      }
    }
  }
}

extern "C" void kernel_launch(void* const* d_in, const int* in_sizes, int n_in,
                              void* d_out, int out_size, void* d_ws, size_t ws_size,
                              hipStream_t stream) {
  const float* Q = (const float*)d_in[0];
  const float* K = (const float*)d_in[1];
  const float* V = (const float*)d_in[2];
  float* out = (float*)d_out;

  char* ws = (char*)d_ws;
  size_t off = 0;
  auto alloc = [&](size_t bytes) {
    void* p = ws + off;
    off += (bytes + 255) & ~(size_t)255;
    return p;
  };
  unsigned short* Qp   = (unsigned short*)alloc((size_t)BATCH * SEQ * DIM * 2);
  unsigned short* P    = Qp;  // split-K partials [B][KSPLIT][DIM*DIM] bf16 = 32 MB
  unsigned short* Kt   = (unsigned short*)alloc((size_t)BATCH * SEQ * DIM * 2);
  unsigned short* Vt   = (unsigned short*)alloc((size_t)BATCH * SEQ * DIM * 2);
  unsigned short* KVt  = (unsigned short*)alloc((size_t)BATCH * DIM * DIM * 2);
  float* Ksum = (float*)alloc((size_t)BATCH * DIM * 4);
  float* invZ = (float*)alloc((size_t)BATCH * SEQ * 4);

  hipFuncSetAttribute(reinterpret_cast<const void*>(&gemm256_bt<0, KSPLIT>),
                      hipFuncAttributeMaxDynamicSharedMemorySize, 131072);
  hipFuncSetAttribute(reinterpret_cast<const void*>(&gemm256_bt<1, 1>),
                      hipFuncAttributeMaxDynamicSharedMemorySize, 131072);

  const dim3 tb(32, 8);
  zero_f32<<<(BATCH * DIM + 255) / 256, 256, 0, stream>>>(Ksum, BATCH * DIM);
  phi_transpose<true, true ><<<dim3(DIM / 32, SEQ / 32, BATCH), tb, 0, stream>>>(K, Kt, Ksum, SEQ, DIM);
  phi_transpose<false, false><<<dim3(DIM / 32, SEQ / 32, BATCH), tb, 0, stream>>>(V, Vt, nullptr, SEQ, DIM);
  // gemm1 split-K: P[b][s] = Vt * Kt^T over n-split s   (M=Nc=1024, K=4096)
  gemm256_bt<0, KSPLIT><<<(DIM / 256) * (DIM / 256) * BATCH * KSPLIT, 512, 131072, stream>>>(
      Vt, Kt, P, nullptr, DIM, DIM, SEQ, DIM / 256, DIM / 256);
  reduce_kv<<<dim3(DIM * DIM / (256 * 8), BATCH), 256, 0, stream>>>(P, KVt);
  // phi(Q) cast + fused Z (after reduce: overwrites P region)
  phi_cast_qz<<<BATCH * SEQ / 4, 256, 0, stream>>>(Q, Ksum, Qp, invZ);
  // gemm2: out = (Qp * KVt^T) * invZ   (M=4096, Nc=1024, K=1024)
  gemm256_bt<1, 1><<<(DIM / 256) * (SEQ / 256) * BATCH, 512, 131072, stream>>>(
      Qp, KVt, out, invZ, SEQ, DIM, DIM, DIM / 256, SEQ / 256);
}